// Round 6
// baseline (199.121 us; speedup 1.0000x reference)
//
#include <hip/hip_runtime.h>
#include <cfloat>

// Problem constants: M=N=64 grid, DIM=512, B=4096, SIGMA=32
#define DIMK 512
#define MN   4096
#define BATCH 4096
#define BK 32
#define NCHUNK 64   // per-row argmin partials: 64 chunks of 64 cols

typedef _Float16 half8_t __attribute__((ext_vector_type(8)));
typedef _Float16 half4_t __attribute__((ext_vector_type(4)));
typedef float f32x4 __attribute__((ext_vector_type(4)));

// async global->LDS, 16B per lane; LDS dest is wave-uniform base + lane*16
#define GLD16(gp, lp) __builtin_amdgcn_global_load_lds( \
    (const __attribute__((address_space(1))) void*)(gp), \
    (__attribute__((address_space(3))) void*)(lp), 16, 0, 0)

// ---------------------------------------------------------------------------
// fp32 -> (hi, mid) f16 split: a = hi + mid + O(2^-22 |a|).
// Blocks < 2048 convert X; blocks >= 2048 convert W AND compute w2 row sums
// (each block covers exactly 2 rows of 512).
// ---------------------------------------------------------------------------
__global__ __launch_bounds__(256) void convert_kernel(
        const float* __restrict__ X, const float* __restrict__ W,
        _Float16* __restrict__ Xhi, _Float16* __restrict__ Xmi,
        _Float16* __restrict__ Whi, _Float16* __restrict__ Wmi,
        float* __restrict__ w2) {
    const int blk = blockIdx.x;
    const int t   = threadIdx.x;
    const bool isW = blk >= 2048;
    const float* src = isW ? W : X;
    _Float16* hi  = isW ? Whi : Xhi;
    _Float16* mid = isW ? Wmi : Xmi;
    const size_t base = (size_t)(isW ? blk - 2048 : blk) * 1024;
    const size_t idx  = base + (size_t)t * 4;
    float4 v = *(const float4*)(src + idx);
    _Float16 h0 = (_Float16)v.x, h1 = (_Float16)v.y,
             h2 = (_Float16)v.z, h3 = (_Float16)v.w;
    half4_t hv = {h0, h1, h2, h3};
    half4_t mv = {(_Float16)(v.x - (float)h0), (_Float16)(v.y - (float)h1),
                  (_Float16)(v.z - (float)h2), (_Float16)(v.w - (float)h3)};
    *(half4_t*)(hi + idx) = hv;
    *(half4_t*)(mid + idx) = mv;
    if (isW) {
        __shared__ float ws[4];
        float s = v.x*v.x + v.y*v.y + v.z*v.z + v.w*v.w;
        int lane = t & 63;
#pragma unroll
        for (int o = 32; o > 0; o >>= 1) s += __shfl_down(s, o);
        if (lane == 0) ws[t >> 6] = s;
        __syncthreads();
        size_t row = base >> 9;          // (blk-2048)*2
        if (t == 0)   w2[row]     = ws[0] + ws[1];
        if (t == 128) w2[row + 1] = ws[2] + ws[3];
    }
}

// ---------------------------------------------------------------------------
// MFMA score kernel: s[b,k] = w2[k] - 2*dot(X[b],W[k]) via 3-product f16
// hi/mid split (pre-converted arrays).
//   A (X): global_load_lds -> LDS, double-buffered 2x16KB, ONE barrier/iter.
//   B (W): global f16 -> VGPR fragments directly (fragment layout == a clean
//     16B/lane load), register double-buffered, NO barrier coupling. B(k+1)
//     is issued ~one full MFMA phase before the barrier that drains it.
//   Per-(row, 64-col chunk) argmin partials to workspace.
// grid (32,32), 256 threads; wave w: m-half wm=w>>1, n-half wn=w&1, 64x64
// region = 4x4 MFMA tiles of 16x16x32.
// ---------------------------------------------------------------------------
__global__ __launch_bounds__(256, 2) void score_kernel(
        const _Float16* __restrict__ Xhi, const _Float16* __restrict__ Xmi,
        const _Float16* __restrict__ Whi, const _Float16* __restrict__ Wmi,
        const float* __restrict__ w2,
        float* __restrict__ pval, int* __restrict__ pidx) {
    // A dbuf: each buf = hi[4096] | mid[4096] f16 (16 KB); 32 KB total
    __shared__ __align__(16) _Float16 lds[2][8192];

    const int t    = threadIdx.x;
    const int lane = t & 63;
    const int w    = t >> 6;
    const int wm   = w >> 1;
    const int wn   = w & 1;
    const int m0   = blockIdx.y * 128;
    const int n0   = blockIdx.x * 128;
    const int r16  = lane & 15;
    const int oct  = lane >> 4;     // k-octet 0..3

    f32x4 acc[4][4];
#pragma unroll
    for (int i = 0; i < 4; i++)
#pragma unroll
        for (int j = 0; j < 4; j++) acc[i][j] = (f32x4){0.f, 0.f, 0.f, 0.f};

    // A staging: wave w stages row-groups (2w, 2w+1), hi+mid. Lane l deposits
    // at lane*16B inside the group's 1KB LDS block == A-fragment layout
    // (row = l&15, k = (l>>4)*8 + e).
    const _Float16* gAh0 = Xhi + (size_t)(m0 + (2 * w + 0) * 16 + r16) * DIMK + oct * 8;
    const _Float16* gAh1 = Xhi + (size_t)(m0 + (2 * w + 1) * 16 + r16) * DIMK + oct * 8;
    const _Float16* gAm0 = Xmi + (size_t)(m0 + (2 * w + 0) * 16 + r16) * DIMK + oct * 8;
    const _Float16* gAm1 = Xmi + (size_t)(m0 + (2 * w + 1) * 16 + r16) * DIMK + oct * 8;
    const int dh0 = (2 * w + 0) * 512 + lane * 8;          // hi region
    const int dh1 = (2 * w + 1) * 512 + lane * 8;
    const int dm0 = 4096 + dh0;                            // mid region
    const int dm1 = 4096 + dh1;

    // B fragment pointers per n-tile j: lane l reads 16B at
    // row (n0 + wn*64 + j*16 + l&15), k-offset (l>>4)*8.
    const _Float16* gBh[4];
    const _Float16* gBm[4];
#pragma unroll
    for (int j = 0; j < 4; j++) {
        size_t off = (size_t)(n0 + wn * 64 + j * 16 + r16) * DIMK + oct * 8;
        gBh[j] = Whi + off;
        gBm[j] = Wmi + off;
    }

    // ---- prologue: A(k=0) -> LDS buf0; B(k=0) -> current regs ----
    GLD16(gAh0, &lds[0][dh0]);
    GLD16(gAh1, &lds[0][dh1]);
    GLD16(gAm0, &lds[0][dm0]);
    GLD16(gAm1, &lds[0][dm1]);
    half8_t bhc[4], bmc[4];
#pragma unroll
    for (int j = 0; j < 4; j++) {
        bhc[j] = *(const half8_t*)(gBh[j]);
        bmc[j] = *(const half8_t*)(gBm[j]);
    }
    __syncthreads();                 // drains prologue A deposits

    int cur = 0;
#pragma unroll 2
    for (int k0 = 0; k0 < DIMK; k0 += BK) {
        const bool more = (k0 + BK) < DIMK;
        const int  nk   = more ? (k0 + BK) : 0;   // clamp: last-iter loads unused
        // --- A(k+1) -> alternate LDS buffer (async, drained at next barrier) ---
        if (more) {
            GLD16(gAh0 + nk, &lds[cur ^ 1][dh0]);
            GLD16(gAh1 + nk, &lds[cur ^ 1][dh1]);
            GLD16(gAm0 + nk, &lds[cur ^ 1][dm0]);
            GLD16(gAm1 + nk, &lds[cur ^ 1][dm1]);
        }
        // --- B(k+1) -> next regs (plain VGPR loads, completed during MFMA) ---
        half8_t bhn[4], bmn[4];
#pragma unroll
        for (int j = 0; j < 4; j++) {
            bhn[j] = *(const half8_t*)(gBh[j] + nk);
            bmn[j] = *(const half8_t*)(gBm[j] + nk);
        }
        // --- A(k) fragments from LDS ---
        half8_t ah[4], am[4];
#pragma unroll
        for (int i = 0; i < 4; i++) {
            ah[i] = *(const half8_t*)&lds[cur][(wm * 4 + i) * 512 + lane * 8];
            am[i] = *(const half8_t*)&lds[cur][4096 + (wm * 4 + i) * 512 + lane * 8];
        }
        // --- 48 MFMA on current B regs ---
#pragma unroll
        for (int i = 0; i < 4; i++)
#pragma unroll
            for (int j = 0; j < 4; j++) {
                acc[i][j] = __builtin_amdgcn_mfma_f32_16x16x32_f16(am[i], bhc[j], acc[i][j], 0, 0, 0);
                acc[i][j] = __builtin_amdgcn_mfma_f32_16x16x32_f16(ah[i], bmc[j], acc[i][j], 0, 0, 0);
                acc[i][j] = __builtin_amdgcn_mfma_f32_16x16x32_f16(ah[i], bhc[j], acc[i][j], 0, 0, 0);
            }
        // --- rotate B regs ---
#pragma unroll
        for (int j = 0; j < 4; j++) { bhc[j] = bhn[j]; bmc[j] = bmn[j]; }
        cur ^= 1;
        __syncthreads();   // A(k+1) deposits visible; all reads of old buf done
    }

    // ---- per-row argmin over this wave's 64 cols ----
    // D layout: col = lane&15, row = (lane>>4)*4 + v   (m89/m91 verified)
    float w2v[4];
    int   ncol[4];
#pragma unroll
    for (int j = 0; j < 4; j++) {
        ncol[j] = n0 + wn * 64 + j * 16 + r16;
        w2v[j]  = w2[ncol[j]];
    }
#pragma unroll
    for (int i = 0; i < 4; i++)
#pragma unroll
        for (int v = 0; v < 4; v++) {
            float bv = FLT_MAX;
            int   bi = 0x7FFFFFFF;
#pragma unroll
            for (int j = 0; j < 4; j++) {        // j ascending -> ties keep lower n
                float s = w2v[j] - 2.0f * acc[i][j][v];
                if (s < bv) { bv = s; bi = ncol[j]; }
            }
#pragma unroll
            for (int mask = 1; mask <= 8; mask <<= 1) {   // reduce over 16 col-lanes
                float ov = __shfl_xor(bv, mask);
                int   oi = __shfl_xor(bi, mask);
                if (ov < bv || (ov == bv && oi < bi)) { bv = ov; bi = oi; }
            }
            if (r16 == 0) {
                int m = m0 + wm * 64 + i * 16 + oct * 4 + v;
                int chunk = blockIdx.x * 2 + wn;
                pval[(size_t)m * NCHUNK + chunk] = bv;
                pidx[(size_t)m * NCHUNK + chunk] = bi;
            }
        }
}

// ---------------------------------------------------------------------------
// Final: reduce 64 partials/row -> BMU, separable Gaussian, write 4096 floats.
// ---------------------------------------------------------------------------
__global__ __launch_bounds__(256) void epilogue_kernel(
        const float* __restrict__ pval, const int* __restrict__ pidx,
        const int* __restrict__ decay_p, const int* __restrict__ it_p,
        float* __restrict__ out) {
    __shared__ float er[64];
    __shared__ float ec[64];
    __shared__ int   s_idx;
    const int b = blockIdx.x;
    const int t = threadIdx.x;

    if (t < 64) {
        float v  = pval[(size_t)b * NCHUNK + t];
        int   ii = pidx[(size_t)b * NCHUNK + t];
#pragma unroll
        for (int mask = 1; mask <= 32; mask <<= 1) {
            float ov = __shfl_xor(v, mask);
            int   oi = __shfl_xor(ii, mask);
            if (ov < v || (ov == v && oi < ii)) { v = ov; ii = oi; }
        }
        if (t == 0) s_idx = ii;
    }
    __syncthreads();
    const int r = s_idx >> 6;
    const int c = s_idx & 63;
    const float lr  = expf(-(float)(*it_p) / (float)(*decay_p));
    const float so  = 32.0f * lr;          // SIGMA = 32
    const float inv = 1.0f / (so * so);
    if (t < 64) {
        float d = (float)(t - r);
        er[t] = expf(-d * d * inv);
    } else if (t < 128) {
        int j = t - 64;
        float d = (float)(j - c);
        ec[j] = expf(-d * d * inv);
    }
    __syncthreads();
    float4* out4 = (float4*)(out + (size_t)b * 4096);
#pragma unroll
    for (int qq = 0; qq < 4; qq++) {
        int f  = t + 256 * qq;
        int i  = f >> 4;
        int j0 = (f & 15) * 4;
        float e = er[i];
        out4[f] = make_float4(e * ec[j0], e * ec[j0 + 1],
                              e * ec[j0 + 2], e * ec[j0 + 3]);
    }
}

// ---------------------------------------------------------------------------
extern "C" void kernel_launch(void* const* d_in, const int* in_sizes, int n_in,
                              void* d_out, int out_size, void* d_ws, size_t ws_size,
                              hipStream_t stream) {
    const float* X       = (const float*)d_in[0];   // [4096,512]
    const float* W       = (const float*)d_in[1];   // [4096,512]
    const int*   decay_p = (const int*)d_in[3];
    const int*   it_p    = (const int*)d_in[4];
    float* out = (float*)d_out;

    // ws: Xhi|Xmi|Whi|Wmi (4MB each f16) | w2 16KB | pval 1MB | pidx 1MB
    _Float16* Xhi = (_Float16*)d_ws;
    _Float16* Xmi = Xhi + (size_t)BATCH * DIMK;
    _Float16* Whi = Xmi + (size_t)BATCH * DIMK;
    _Float16* Wmi = Whi + (size_t)MN * DIMK;
    float*    w2  = (float*)(Wmi + (size_t)MN * DIMK);
    float*    pval = w2 + MN;
    int*      pidx = (int*)(pval + (size_t)BATCH * NCHUNK);

    convert_kernel<<<4096, 256, 0, stream>>>(X, W, Xhi, Xmi, Whi, Wmi, w2);
    score_kernel<<<dim3(32, 32), 256, 0, stream>>>(Xhi, Xmi, Whi, Wmi, w2, pval, pidx);
    epilogue_kernel<<<BATCH, 256, 0, stream>>>(pval, pidx, decay_p, it_p, out);
}